// Round 4
// baseline (147.984 us; speedup 1.0000x reference)
//
#include <hip/hip_runtime.h>

// GraphConv fused pipeline, v6: phase D rebuilt as a flat per-wave chunk
// list with an explicit 2-deep software pipeline (named register sets).
// Evidence trail:
//  - v2/v4/v5 identical: main 49.5 us, VGPR 60 in ALL of them -- the
//    pressure-minimizing scheduler interleaves load->use regardless of
//    8-deep source batching (v4) or a raised VGPR cap via
//    __launch_bounds__(256,3) (v5). Overlap must be structural.
//  - arithmetic: serialized gathers = 8x400cy x 16 nodes ~ 21 us exposed
//    latency per wave (matches main's unexplained bulk); 16-in-flight
//    pipeline -> ~4 us.
// Structure: chunk = (local dst d, e0) covering srcs[e0..e0+32); per-wave
// chunk list built after phase B (mean 16 chunks, cap 96). Pipeline:
// issue loads for chunk j+1 into fB0..7, consume chunk j from fA0..7,
// swap via explicit 2x unroll (no runtime-indexed register arrays).
// aggT is now accumulated (zero-init in phase 0) so multi-chunk nodes
// (deg>32, ~5 nodes globally) compose correctly.
// Constructs deliberately avoided: `#pragma unroll 1` (present in all three
// container-failure rounds R11-R13, absent from every round that ran).

#define FEAT 64     // feature dim (F_IN == F_OUT)
#define TNODES 64   // nodes per destination tile
#define TCAP 2048   // per-tile bucket capacity (mean 1024, ~32 sigma margin)
#define KPAD 65     // k-major LDS row stride (floats)
#define CSTR 16     // tile counter stride: one counter per 64 B line
#define TMAX 1024   // max tiles in binner LDS tables
#define GBIN 256    // binner grid
#define CCAP 96     // per-wave chunk-list capacity (worst case 16+2048/32=80)

// prep: WT[k][o] = W[o][k] for both weight matrices + zero tile counters
__global__ __launch_bounds__(256) void gcv2_prep(
    const float* __restrict__ W_rel, const float* __restrict__ W_root,
    float* __restrict__ WTrel, float* __restrict__ WTroot,
    int* __restrict__ tcnt, int n_cnt) {
  const int idx = blockIdx.x * 256 + threadIdx.x;
  if (idx < FEAT * FEAT) {
    const int o = idx >> 6, k = idx & 63;
    WTrel[k * FEAT + o] = W_rel[idx];
    WTroot[k * FEAT + o] = W_root[idx];
  }
  for (int i = idx; i < n_cnt; i += gridDim.x * 256) tcnt[i] = 0;
}

// binner: per-block LDS histogram -> one global atomic per (block,tile)
// region reservation -> dense packed writes (kills partial-line writeback).
// entry = dst<<16 | src  (valid since n_nodes = 50000 < 65536)
__global__ __launch_bounds__(256) void gcv2_bin(
    const int* __restrict__ eidx, int* __restrict__ tcnt,
    unsigned* __restrict__ tbuf, int n_edges, int n_tiles) {
  __shared__ int bh[TMAX];
  __shared__ int bbase[TMAX];

  const int t = threadIdx.x;
  for (int i = t; i < n_tiles; i += 256) bh[i] = 0;
  __syncthreads();

  const int per = (n_edges + gridDim.x - 1) / gridDim.x;
  const int e0 = blockIdx.x * per;
  const int e1 = min(e0 + per, n_edges);

  for (int e = e0 + t; e < e1; e += 256)
    atomicAdd(&bh[eidx[n_edges + e] >> 6], 1);
  __syncthreads();

  for (int i = t; i < n_tiles; i += 256) {
    const int c = bh[i];
    bbase[i] = (c > 0) ? atomicAdd(&tcnt[i * CSTR], c) : 0;
    bh[i] = 0;
  }
  __syncthreads();

  for (int e = e0 + t; e < e1; e += 256) {
    const int s = eidx[e];
    const int d = eidx[n_edges + e];
    const int tl = d >> 6;
    const int p = bbase[tl] + atomicAdd(&bh[tl], 1);
    if (p < TCAP)
      tbuf[(size_t)tl * TCAP + p] = ((unsigned)d << 16) | (unsigned)s;
  }
}

// fused per-tile: counting sort by local dst -> chunk-list build ->
// 2-deep pipelined gather -> register-blocked GEMM + bias + ReLU.
__global__ __launch_bounds__(256, 3) void gcv2_main(
    const float* __restrict__ x,
    const float* __restrict__ WTrel,   // [FEAT][FEAT] k-major
    const float* __restrict__ b_rel,   // [FEAT]
    const float* __restrict__ WTroot,  // [FEAT][FEAT] k-major
    const int* __restrict__ tcnt,
    const unsigned* __restrict__ tbuf,
    float* __restrict__ out, int n_nodes) {
  __shared__ float aggT[FEAT * KPAD];         // k-major: aggT[k*KPAD + r]
  __shared__ float xT[FEAT * KPAD];           // k-major self tile
  __shared__ unsigned short srcs[TCAP + 64];  // dst-sorted srcs (+pad)
  __shared__ int sh[TNODES];
  __shared__ int soff[TNODES + 1];
  __shared__ int scur[TNODES];
  __shared__ int cdesc[4 * CCAP];             // per-wave chunk descriptors
  __shared__ int ncK[4];                      // per-wave chunk counts

  const int t = threadIdx.x;
  const int lane = t & 63;
  const int w = t >> 6;
  const int tile = blockIdx.x;
  const int node0 = tile * TNODES;
  const int cnt = min(tcnt[tile * CSTR], TCAP);
  const unsigned* lst = tbuf + (size_t)tile * TCAP;

  // phase 0: zero histogram + aggT, zero srcs pad, stage xT (k-major)
  if (t < TNODES) sh[t] = 0;
  if (t < 64 && cnt + t < TCAP + 64) srcs[cnt + t] = 0;
  for (int i = t; i < FEAT * KPAD; i += 256) aggT[i] = 0.f;
  {
    const int c4 = t & 15;
    const int rr = t >> 4;
#pragma unroll
    for (int p = 0; p < 4; ++p) {
      const int r = p * 16 + rr;
      const int gi = node0 + r;
      float4 v = make_float4(0.f, 0.f, 0.f, 0.f);
      if (gi < n_nodes) v = *(const float4*)(x + (size_t)gi * FEAT + c4 * 4);
      xT[(c4 * 4 + 0) * KPAD + r] = v.x;
      xT[(c4 * 4 + 1) * KPAD + r] = v.y;
      xT[(c4 * 4 + 2) * KPAD + r] = v.z;
      xT[(c4 * 4 + 3) * KPAD + r] = v.w;
    }
  }
  __syncthreads();

  // phase A: histogram by local dst (int LDS atomics)
  for (int i = t; i < cnt; i += 256) atomicAdd(&sh[(lst[i] >> 16) & 63], 1);
  __syncthreads();

  // phase B: 64-wide exclusive scan in wave 0
  if (w == 0) {
    int v = sh[lane];
    int s = v;
#pragma unroll
    for (int d = 1; d < 64; d <<= 1) {
      int u = __shfl_up(s, d, 64);
      if (lane >= d) s += u;
    }
    soff[lane] = s - v;
    scur[lane] = s - v;
    if (lane == 63) soff[64] = s;  // == cnt
  }
  __syncthreads();

  // phase B2: per-wave chunk-list build (lanes 0..15 own 1 node each)
  {
    int myc = 0, jb0 = 0;
    const int nd = w * 16 + (lane & 15);  // local node id 0..63
    if (lane < 16) {
      jb0 = soff[nd];
      const int deg = soff[nd + 1] - jb0;
      myc = (deg + 31) >> 5;  // ceil(deg/32)
    }
    int sc = myc;  // inclusive scan over 16-lane groups
#pragma unroll
    for (int dlt = 1; dlt < 16; dlt <<= 1) {
      const int u = __shfl_up(sc, dlt, 16);
      if ((lane & 15) >= dlt) sc += u;
    }
    const int pos = sc - myc;
    const int tot = __shfl(sc, 15, 64);  // lane 15 holds the wave total
    if (lane == 0) ncK[w] = tot;
    if (lane < 16) {
      for (int c = 0; c < myc; ++c)
        cdesc[w * CCAP + pos + c] = (nd << 16) | (jb0 + c * 32);
    }
  }

  // phase C: counting-sort scatter into srcs[]
  for (int i = t; i < cnt; i += 256) {
    const unsigned e = lst[i];
    const int d = (int)((e >> 16) & 63);
    srcs[atomicAdd(&scur[d], 1)] = (unsigned short)(e & 0xFFFFu);
  }
  __syncthreads();

  // phase D: 2-deep pipelined gather over the wave's chunk list.
  // lanes = 4 edge-slots x 16 feature-quads; 8 float4 loads per chunk;
  // chunk j+1's loads issued before chunk j's consume -> 16 in flight.
  const int slot = lane >> 4;
  const int fq = lane & 15;
  const int nc = ncK[w];
  const int cbase = w * CCAP;

#define GC_ISSUE(DSC, F0, F1, F2, F3, F4, F5, F6, F7)                        \
  {                                                                          \
    const int e0_ = (DSC) & 0xFFFF;                                          \
    const int je_ = soff[((DSC) >> 16) + 1];                                 \
    const int m_ = je_ - e0_;                                                \
    const int j0_ = (slot < m_) ? e0_ + slot : cnt;                          \
    const int j1_ = (4 + slot < m_) ? e0_ + 4 + slot : cnt;                  \
    const int j2_ = (8 + slot < m_) ? e0_ + 8 + slot : cnt;                  \
    const int j3_ = (12 + slot < m_) ? e0_ + 12 + slot : cnt;                \
    const int j4_ = (16 + slot < m_) ? e0_ + 16 + slot : cnt;                \
    const int j5_ = (20 + slot < m_) ? e0_ + 20 + slot : cnt;                \
    const int j6_ = (24 + slot < m_) ? e0_ + 24 + slot : cnt;                \
    const int j7_ = (28 + slot < m_) ? e0_ + 28 + slot : cnt;                \
    const int s0_ = (int)srcs[j0_];                                          \
    const int s1_ = (int)srcs[j1_];                                          \
    const int s2_ = (int)srcs[j2_];                                          \
    const int s3_ = (int)srcs[j3_];                                          \
    const int s4_ = (int)srcs[j4_];                                          \
    const int s5_ = (int)srcs[j5_];                                          \
    const int s6_ = (int)srcs[j6_];                                          \
    const int s7_ = (int)srcs[j7_];                                          \
    F0 = *(const float4*)(x + (size_t)s0_ * FEAT + fq * 4);                  \
    F1 = *(const float4*)(x + (size_t)s1_ * FEAT + fq * 4);                  \
    F2 = *(const float4*)(x + (size_t)s2_ * FEAT + fq * 4);                  \
    F3 = *(const float4*)(x + (size_t)s3_ * FEAT + fq * 4);                  \
    F4 = *(const float4*)(x + (size_t)s4_ * FEAT + fq * 4);                  \
    F5 = *(const float4*)(x + (size_t)s5_ * FEAT + fq * 4);                  \
    F6 = *(const float4*)(x + (size_t)s6_ * FEAT + fq * 4);                  \
    F7 = *(const float4*)(x + (size_t)s7_ * FEAT + fq * 4);                  \
  }

#define GC_CONSUME(DSC, F0, F1, F2, F3, F4, F5, F6, F7)                      \
  {                                                                          \
    const int d_ = (DSC) >> 16;                                              \
    const int e0_ = (DSC) & 0xFFFF;                                          \
    const int m_ = soff[d_ + 1] - e0_;                                       \
    float4 acc = make_float4(0.f, 0.f, 0.f, 0.f);                            \
    acc.x += (slot < m_ ? F0.x : 0.f); acc.y += (slot < m_ ? F0.y : 0.f);    \
    acc.z += (slot < m_ ? F0.z : 0.f); acc.w += (slot < m_ ? F0.w : 0.f);    \
    acc.x += (4 + slot < m_ ? F1.x : 0.f);                                   \
    acc.y += (4 + slot < m_ ? F1.y : 0.f);                                   \
    acc.z += (4 + slot < m_ ? F1.z : 0.f);                                   \
    acc.w += (4 + slot < m_ ? F1.w : 0.f);                                   \
    acc.x += (8 + slot < m_ ? F2.x : 0.f);                                   \
    acc.y += (8 + slot < m_ ? F2.y : 0.f);                                   \
    acc.z += (8 + slot < m_ ? F2.z : 0.f);                                   \
    acc.w += (8 + slot < m_ ? F2.w : 0.f);                                   \
    acc.x += (12 + slot < m_ ? F3.x : 0.f);                                  \
    acc.y += (12 + slot < m_ ? F3.y : 0.f);                                  \
    acc.z += (12 + slot < m_ ? F3.z : 0.f);                                  \
    acc.w += (12 + slot < m_ ? F3.w : 0.f);                                  \
    acc.x += (16 + slot < m_ ? F4.x : 0.f);                                  \
    acc.y += (16 + slot < m_ ? F4.y : 0.f);                                  \
    acc.z += (16 + slot < m_ ? F4.z : 0.f);                                  \
    acc.w += (16 + slot < m_ ? F4.w : 0.f);                                  \
    acc.x += (20 + slot < m_ ? F5.x : 0.f);                                  \
    acc.y += (20 + slot < m_ ? F5.y : 0.f);                                  \
    acc.z += (20 + slot < m_ ? F5.z : 0.f);                                  \
    acc.w += (20 + slot < m_ ? F5.w : 0.f);                                  \
    acc.x += (24 + slot < m_ ? F6.x : 0.f);                                  \
    acc.y += (24 + slot < m_ ? F6.y : 0.f);                                  \
    acc.z += (24 + slot < m_ ? F6.z : 0.f);                                  \
    acc.w += (24 + slot < m_ ? F6.w : 0.f);                                  \
    acc.x += (28 + slot < m_ ? F7.x : 0.f);                                  \
    acc.y += (28 + slot < m_ ? F7.y : 0.f);                                  \
    acc.z += (28 + slot < m_ ? F7.z : 0.f);                                  \
    acc.w += (28 + slot < m_ ? F7.w : 0.f);                                  \
    acc.x += __shfl_xor(acc.x, 16, 64); acc.y += __shfl_xor(acc.y, 16, 64);  \
    acc.z += __shfl_xor(acc.z, 16, 64); acc.w += __shfl_xor(acc.w, 16, 64);  \
    acc.x += __shfl_xor(acc.x, 32, 64); acc.y += __shfl_xor(acc.y, 32, 64);  \
    acc.z += __shfl_xor(acc.z, 32, 64); acc.w += __shfl_xor(acc.w, 32, 64);  \
    if (slot == 0) {                                                         \
      aggT[(fq * 4 + 0) * KPAD + d_] += acc.x;                               \
      aggT[(fq * 4 + 1) * KPAD + d_] += acc.y;                               \
      aggT[(fq * 4 + 2) * KPAD + d_] += acc.z;                               \
      aggT[(fq * 4 + 3) * KPAD + d_] += acc.w;                               \
    }                                                                        \
  }

  {
    int descA = 0, descB = 0;
    float4 fA0, fA1, fA2, fA3, fA4, fA5, fA6, fA7;
    float4 fB0, fB1, fB2, fB3, fB4, fB5, fB6, fB7;
    if (nc > 0) {
      descA = cdesc[cbase];
      GC_ISSUE(descA, fA0, fA1, fA2, fA3, fA4, fA5, fA6, fA7);
    }
    for (int j = 0; j < nc; j += 2) {
      const bool hasB = (j + 1 < nc);
      if (hasB) {
        descB = cdesc[cbase + j + 1];
        GC_ISSUE(descB, fB0, fB1, fB2, fB3, fB4, fB5, fB6, fB7);
      }
      GC_CONSUME(descA, fA0, fA1, fA2, fA3, fA4, fA5, fA6, fA7);
      if (hasB) {
        if (j + 2 < nc) {
          descA = cdesc[cbase + j + 2];
          GC_ISSUE(descA, fA0, fA1, fA2, fA3, fA4, fA5, fA6, fA7);
        }
        GC_CONSUME(descB, fB0, fB1, fB2, fB3, fB4, fB5, fB6, fB7);
      }
    }
  }
  __syncthreads();

  // phase E: out[r][o] = relu(b[o] + sum_k aggT[k][r]*WTrel[k][o]
  //                                  + sum_k xT[k][r]*WTroot[k][o])
  const int oq = t & 15, rq = t >> 4;
  const int o0 = oq * 4, r0 = rq * 4;
  const float4 bias = *(const float4*)(b_rel + o0);
  float acc[4][4];
#pragma unroll
  for (int ri = 0; ri < 4; ++ri) {
    acc[ri][0] = bias.x; acc[ri][1] = bias.y;
    acc[ri][2] = bias.z; acc[ri][3] = bias.w;
  }
#pragma unroll 4
  for (int k = 0; k < FEAT; ++k) {
    const float4 wr = *(const float4*)(WTrel + k * FEAT + o0);
    const float4 wo = *(const float4*)(WTroot + k * FEAT + o0);
    const float a0 = aggT[k * KPAD + r0 + 0], a1 = aggT[k * KPAD + r0 + 1];
    const float a2 = aggT[k * KPAD + r0 + 2], a3 = aggT[k * KPAD + r0 + 3];
    const float x0 = xT[k * KPAD + r0 + 0], x1 = xT[k * KPAD + r0 + 1];
    const float x2 = xT[k * KPAD + r0 + 2], x3 = xT[k * KPAD + r0 + 3];
    acc[0][0] += a0 * wr.x + x0 * wo.x; acc[0][1] += a0 * wr.y + x0 * wo.y;
    acc[0][2] += a0 * wr.z + x0 * wo.z; acc[0][3] += a0 * wr.w + x0 * wo.w;
    acc[1][0] += a1 * wr.x + x1 * wo.x; acc[1][1] += a1 * wr.y + x1 * wo.y;
    acc[1][2] += a1 * wr.z + x1 * wo.z; acc[1][3] += a1 * wr.w + x1 * wo.w;
    acc[2][0] += a2 * wr.x + x2 * wo.x; acc[2][1] += a2 * wr.y + x2 * wo.y;
    acc[2][2] += a2 * wr.z + x2 * wo.z; acc[2][3] += a2 * wr.w + x2 * wo.w;
    acc[3][0] += a3 * wr.x + x3 * wo.x; acc[3][1] += a3 * wr.y + x3 * wo.y;
    acc[3][2] += a3 * wr.z + x3 * wo.z; acc[3][3] += a3 * wr.w + x3 * wo.w;
  }
#pragma unroll
  for (int ri = 0; ri < 4; ++ri) {
    const int gi = node0 + r0 + ri;
    if (gi < n_nodes) {
      float4 o4;
      o4.x = fmaxf(acc[ri][0], 0.f); o4.y = fmaxf(acc[ri][1], 0.f);
      o4.z = fmaxf(acc[ri][2], 0.f); o4.w = fmaxf(acc[ri][3], 0.f);
      *(float4*)(out + (size_t)gi * FEAT + o0) = o4;
    }
  }
}

extern "C" void kernel_launch(void* const* d_in, const int* in_sizes, int n_in,
                              void* d_out, int out_size, void* d_ws, size_t ws_size,
                              hipStream_t stream) {
  const float* x      = (const float*)d_in[0];  // [N, 64]
  const float* W_rel  = (const float*)d_in[1];  // [64, 64]
  const float* b_rel  = (const float*)d_in[2];  // [64]
  const float* W_root = (const float*)d_in[3];  // [64, 64]
  const int* eidx     = (const int*)d_in[4];    // [2, E]

  const int n_nodes = in_sizes[0] / FEAT;
  const int n_edges = in_sizes[4] / 2;
  const int n_tiles = (n_nodes + TNODES - 1) / TNODES;  // 782

  int* tcnt      = (int*)d_ws;                                   // [n_tiles*CSTR]
  unsigned* tbuf = (unsigned*)(tcnt + (size_t)n_tiles * CSTR);   // [n_tiles*TCAP]
  float* WTrel   = (float*)(tbuf + (size_t)n_tiles * TCAP);
  float* WTroot  = WTrel + FEAT * FEAT;

  float* out = (float*)d_out;

  const int n_cnt = n_tiles * CSTR;
  const int gPrep = (n_cnt + 255) / 256;
  gcv2_prep<<<gPrep, 256, 0, stream>>>(W_rel, W_root, WTrel, WTroot, tcnt,
                                       n_cnt);

  gcv2_bin<<<GBIN, 256, 0, stream>>>(eidx, tcnt, tbuf, n_edges, n_tiles);

  gcv2_main<<<n_tiles, 256, 0, stream>>>(x, WTrel, b_rel, WTroot, tcnt, tbuf,
                                         out, n_nodes);
}